// Round 2
// baseline (1101.904 us; speedup 1.0000x reference)
//
#include <hip/hip_runtime.h>

#define N_TOT      150000
#define N_USER     50000
#define N_EDGE     2400000
#define DIM        64
#define OUT_STRIDE 256
#define SLOPE      0.2f
#define NB_SCAN    ((N_TOT + 255) / 256)   // 587

// ---- ws layout ----
// egoA   : [N,64] fp32  (layer ping)
// egoB   : [N,64] fp32  (layer pong; aliased as rank[E] during CSR build)
// epack  : [E] int2 (col, val_bits)
// row_ptr: [N+1] int
// cnt    : [N] int (histogram counts)
// bsum   : [NB_SCAN] int

__global__ void init_ego(const float* __restrict__ ue, const float* __restrict__ ie,
                         float* __restrict__ ego, float* __restrict__ out) {
    int idx = blockIdx.x * blockDim.x + threadIdx.x;          // float4 index
    if (idx >= N_TOT * DIM / 4) return;
    int n  = idx >> 4;
    int c4 = idx & 15;
    float4 v = (n < N_USER) ? ((const float4*)ue)[idx]
                            : ((const float4*)ie)[idx - N_USER * (DIM / 4)];
    ((float4*)ego)[idx] = v;
    ((float4*)out)[n * (OUT_STRIDE / 4) + c4] = v;
}

// Histogram + per-edge rank in ONE pass: the atomic return value IS the rank.
// 8 edges per thread for more atomic round-trips in flight (latency-bound).
__global__ void hist_rank(const int* __restrict__ rows, int* __restrict__ cnt,
                          int* __restrict__ rank) {
    int t = blockIdx.x * blockDim.x + threadIdx.x;
    if (t >= N_EDGE / 8) return;
    int4 ra = ((const int4*)rows)[2 * t];
    int4 rb = ((const int4*)rows)[2 * t + 1];
    int4 ka, kb;
    ka.x = atomicAdd(&cnt[ra.x], 1);
    ka.y = atomicAdd(&cnt[ra.y], 1);
    ka.z = atomicAdd(&cnt[ra.z], 1);
    ka.w = atomicAdd(&cnt[ra.w], 1);
    kb.x = atomicAdd(&cnt[rb.x], 1);
    kb.y = atomicAdd(&cnt[rb.y], 1);
    kb.z = atomicAdd(&cnt[rb.z], 1);
    kb.w = atomicAdd(&cnt[rb.w], 1);
    ((int4*)rank)[2 * t]     = ka;
    ((int4*)rank)[2 * t + 1] = kb;
}

// Hierarchical scan, stage 1: per-256-chunk exclusive scan + block totals.
__global__ __launch_bounds__(256) void scan_partial(const int* __restrict__ cnt,
                                                    int* __restrict__ row_ptr,
                                                    int* __restrict__ bsum) {
    __shared__ int s[256];
    int tid = threadIdx.x;
    int i = blockIdx.x * 256 + tid;
    int v = (i < N_TOT) ? cnt[i] : 0;
    s[tid] = v;
    __syncthreads();
    for (int off = 1; off < 256; off <<= 1) {                 // Hillis-Steele inclusive
        int t = (tid >= off) ? s[tid - off] : 0;
        __syncthreads();
        s[tid] += t;
        __syncthreads();
    }
    if (i < N_TOT) row_ptr[i] = s[tid] - v;                   // local exclusive
    if (tid == 255) bsum[blockIdx.x] = s[255];
}

// Stage 2: single block scans the NB_SCAN block totals (exclusive, in place).
__global__ __launch_bounds__(1024) void scan_bsums(int* __restrict__ bsum) {
    __shared__ int s[1024];
    int tid = threadIdx.x;
    int v = (tid < NB_SCAN) ? bsum[tid] : 0;
    s[tid] = v;
    __syncthreads();
    for (int off = 1; off < 1024; off <<= 1) {
        int t = (tid >= off) ? s[tid - off] : 0;
        __syncthreads();
        s[tid] += t;
        __syncthreads();
    }
    if (tid < NB_SCAN) bsum[tid] = s[tid] - v;
}

// Stage 3: add block offsets; write final row_ptr.
__global__ __launch_bounds__(256) void add_offsets(int* __restrict__ row_ptr,
                                                   const int* __restrict__ bsum) {
    int i = blockIdx.x * 256 + threadIdx.x;
    if (i < N_TOT) row_ptr[i] += bsum[blockIdx.x];
    if (i == 0) row_ptr[N_TOT] = N_EDGE;
}

// Atomic-free scatter: pos = row_ptr[row] + rank (deterministic).
// 8 edges/thread for more random-write MLP.
__global__ void scatter_edges(const int* __restrict__ rows, const int* __restrict__ cols,
                              const float* __restrict__ vals,
                              const int* __restrict__ row_ptr,
                              const int* __restrict__ rank, int2* __restrict__ epack) {
    int t = blockIdx.x * blockDim.x + threadIdx.x;
    if (t >= N_EDGE / 8) return;
    #pragma unroll
    for (int h = 0; h < 2; ++h) {
        int    f  = 2 * t + h;
        int4   r4 = ((const int4*)rows)[f];
        int4   k4 = ((const int4*)rank)[f];
        int4   c4 = ((const int4*)cols)[f];
        float4 v4 = ((const float4*)vals)[f];
        epack[row_ptr[r4.x] + k4.x] = make_int2(c4.x, __float_as_int(v4.x));
        epack[row_ptr[r4.y] + k4.y] = make_int2(c4.y, __float_as_int(v4.y));
        epack[row_ptr[r4.z] + k4.z] = make_int2(c4.z, __float_as_int(v4.z));
        epack[row_ptr[r4.w] + k4.w] = make_int2(c4.w, __float_as_int(v4.w));
    }
}

// Fused layer: CSR gather -> LDS (transposed) -> dual 64x64 GEMM + LeakyReLU
// + add + l2norm. side never touches global memory. ego double-buffered:
// ego_in frozen (read-only), ego_out disjoint per block -> no race.
__global__ __launch_bounds__(256) void fused_layer(
    const int* __restrict__ row_ptr, const int2* __restrict__ epack,
    const float* __restrict__ ego_in,
    const float* __restrict__ Wg, const float* __restrict__ bgv,
    const float* __restrict__ Wb, const float* __restrict__ bbv,
    float* __restrict__ ego_out, float* __restrict__ out, int layer) {
    __shared__ float sST[DIM][68];     // sST[k][r] = side[R0+r][k]
    __shared__ float sPT[DIM][68];     // sPT[k][r] = (ego_in*side)[R0+r][k]
    __shared__ float sWg[DIM][DIM];
    __shared__ float sWb[DIM][DIM];
    int tid = threadIdx.x;
    int R0  = blockIdx.x * 64;

    #pragma unroll
    for (int it = 0; it < 4; ++it) {                          // stage W matrices
        int f = tid + it * 256;                               // float4 idx 0..1023
        float4 wg = ((const float4*)Wg)[f];
        float4 wb = ((const float4*)Wb)[f];
        int k = f >> 4, c = (f & 15) * 4;
        *(float4*)&sWg[k][c] = wg;
        *(float4*)&sWb[k][c] = wb;
    }

    // ---- gather phase: one wave per row, 16 rows per wave ----
    int wave = tid >> 6;
    int lane = tid & 63;
    int g = lane >> 4;          // edge sub-group 0..3
    int q = lane & 15;          // dim quarter: dims q*4 .. q*4+3
    for (int rr = wave; rr < 64; rr += 4) {
        int row = R0 + rr;                                    // wave-uniform
        float4 acc = make_float4(0.f, 0.f, 0.f, 0.f);
        if (row < N_TOT) {
            int beg = row_ptr[row];
            int end = row_ptr[row + 1];
            int i = beg;
            for (; i + 8 <= end; i += 8) {
                int4 ee = ((const int4*)(epack + i))[g];      // edges i+2g, i+2g+1
                float4 va = ((const float4*)(ego_in + (size_t)ee.x * DIM))[q];
                float4 vb = ((const float4*)(ego_in + (size_t)ee.z * DIM))[q];
                float wa = __int_as_float(ee.y);
                float wb = __int_as_float(ee.w);
                acc.x = fmaf(wa, va.x, acc.x); acc.y = fmaf(wa, va.y, acc.y);
                acc.z = fmaf(wa, va.z, acc.z); acc.w = fmaf(wa, va.w, acc.w);
                acc.x = fmaf(wb, vb.x, acc.x); acc.y = fmaf(wb, vb.y, acc.y);
                acc.z = fmaf(wb, vb.z, acc.z); acc.w = fmaf(wb, vb.w, acc.w);
            }
            for (; i < end; i += 4) {                         // tail: <=7 edges
                if (i + g < end) {
                    int2 e = epack[i + g];
                    float4 v = ((const float4*)(ego_in + (size_t)e.x * DIM))[q];
                    float w = __int_as_float(e.y);
                    acc.x = fmaf(w, v.x, acc.x); acc.y = fmaf(w, v.y, acc.y);
                    acc.z = fmaf(w, v.z, acc.z); acc.w = fmaf(w, v.w, acc.w);
                }
            }
        }
        // combine the 4 edge-groups (lane bits 4 and 5)
        acc.x += __shfl_xor(acc.x, 16, 64); acc.y += __shfl_xor(acc.y, 16, 64);
        acc.z += __shfl_xor(acc.z, 16, 64); acc.w += __shfl_xor(acc.w, 16, 64);
        acc.x += __shfl_xor(acc.x, 32, 64); acc.y += __shfl_xor(acc.y, 32, 64);
        acc.z += __shfl_xor(acc.z, 32, 64); acc.w += __shfl_xor(acc.w, 32, 64);
        if (g == 0) {                                         // lanes 0..15 hold dims q*4..+3
            float4 e4 = make_float4(0.f, 0.f, 0.f, 0.f);
            if (row < N_TOT)
                e4 = *(const float4*)&ego_in[(size_t)row * DIM + q * 4];
            int k0 = q * 4;
            sST[k0 + 0][rr] = acc.x; sST[k0 + 1][rr] = acc.y;
            sST[k0 + 2][rr] = acc.z; sST[k0 + 3][rr] = acc.w;
            sPT[k0 + 0][rr] = acc.x * e4.x; sPT[k0 + 1][rr] = acc.y * e4.y;
            sPT[k0 + 2][rr] = acc.z * e4.z; sPT[k0 + 3][rr] = acc.w * e4.w;
        }
    }
    __syncthreads();

    // ---- GEMM phase ----
    int tx = tid & 15, ty = tid >> 4;
    int c0 = tx * 4, r0 = ty * 4;
    float ag[4][4] = {{0.f}}, ab[4][4] = {{0.f}};
    #pragma unroll 4
    for (int k = 0; k < DIM; ++k) {
        float4 s4 = *(const float4*)&sST[k][r0];
        float4 p4 = *(const float4*)&sPT[k][r0];
        float4 g4 = *(const float4*)&sWg[k][c0];
        float4 b4 = *(const float4*)&sWb[k][c0];
        float ss[4] = {s4.x, s4.y, s4.z, s4.w};
        float pp[4] = {p4.x, p4.y, p4.z, p4.w};
        float gg[4] = {g4.x, g4.y, g4.z, g4.w};
        float bw[4] = {b4.x, b4.y, b4.z, b4.w};
        #pragma unroll
        for (int i = 0; i < 4; ++i)
            #pragma unroll
            for (int j = 0; j < 4; ++j) {
                ag[i][j] = fmaf(ss[i], gg[j], ag[i][j]);
                ab[i][j] = fmaf(pp[i], bw[j], ab[i][j]);
            }
    }

    float4 bg4 = *(const float4*)&bgv[c0];
    float4 bb4 = *(const float4*)&bbv[c0];
    float bgl[4] = {bg4.x, bg4.y, bg4.z, bg4.w};
    float bbl[4] = {bb4.x, bb4.y, bb4.z, bb4.w};

    float ne[4][4];
    float ss2[4];
    #pragma unroll
    for (int i = 0; i < 4; ++i) {
        float s = 0.f;
        #pragma unroll
        for (int j = 0; j < 4; ++j) {
            float g2 = ag[i][j] + bgl[j];
            float b2 = ab[i][j] + bbl[j];
            g2 = g2 > 0.f ? g2 : SLOPE * g2;
            b2 = b2 > 0.f ? b2 : SLOPE * b2;
            float v = g2 + b2;
            ne[i][j] = v;
            s = fmaf(v, v, s);
        }
        ss2[i] = s;
    }
    #pragma unroll
    for (int m = 1; m < 16; m <<= 1) {                        // reduce across tx group
        #pragma unroll
        for (int i = 0; i < 4; ++i) ss2[i] += __shfl_xor(ss2[i], m, 64);
    }

    float* outbase = out + (size_t)(layer + 1) * DIM;
    #pragma unroll
    for (int i = 0; i < 4; ++i) {
        int row = R0 + r0 + i;
        if (row >= N_TOT) break;
        float inv = 1.f / fmaxf(sqrtf(ss2[i]), 1e-12f);
        float4 e4 = make_float4(ne[i][0], ne[i][1], ne[i][2], ne[i][3]);
        float4 o4 = make_float4(ne[i][0] * inv, ne[i][1] * inv, ne[i][2] * inv, ne[i][3] * inv);
        *(float4*)&ego_out[(size_t)row * DIM + c0] = e4;
        *(float4*)&outbase[(size_t)row * OUT_STRIDE + c0] = o4;
    }
}

extern "C" void kernel_launch(void* const* d_in, const int* in_sizes, int n_in,
                              void* d_out, int out_size, void* d_ws, size_t ws_size,
                              hipStream_t stream) {
    const float* ue = (const float*)d_in[0];
    const float* ie = (const float*)d_in[1];
    const float* Wg[3] = {(const float*)d_in[2], (const float*)d_in[6], (const float*)d_in[10]};
    const float* bg[3] = {(const float*)d_in[3], (const float*)d_in[7], (const float*)d_in[11]};
    const float* Wb[3] = {(const float*)d_in[4], (const float*)d_in[8], (const float*)d_in[12]};
    const float* bb[3] = {(const float*)d_in[5], (const float*)d_in[9], (const float*)d_in[13]};
    const float* vals = (const float*)d_in[14];
    const int*  rows  = (const int*)d_in[15];
    const int*  cols  = (const int*)d_in[16];
    float* out = (float*)d_out;

    float* egoA    = (float*)d_ws;
    float* egoB    = egoA + (size_t)N_TOT * DIM;
    int2*  epack   = (int2*)(egoB + (size_t)N_TOT * DIM);
    int*   row_ptr = (int*)(epack + N_EDGE);
    int*   cnt     = row_ptr + (N_TOT + 16);
    int*   bsum    = cnt + N_TOT;
    int*   rank    = (int*)egoB;      // alias: egoB first written in layer 0

    // CSR build (adj constant across layers)
    hipMemsetAsync(cnt, 0, (size_t)N_TOT * sizeof(int), stream);
    hist_rank<<<(N_EDGE / 8 + 255) / 256, 256, 0, stream>>>(rows, cnt, rank);
    scan_partial<<<NB_SCAN, 256, 0, stream>>>(cnt, row_ptr, bsum);
    scan_bsums<<<1, 1024, 0, stream>>>(bsum);
    add_offsets<<<NB_SCAN, 256, 0, stream>>>(row_ptr, bsum);
    scatter_edges<<<(N_EDGE / 8 + 255) / 256, 256, 0, stream>>>(rows, cols, vals,
                                                                row_ptr, rank, epack);

    init_ego<<<(N_TOT * DIM / 4 + 255) / 256, 256, 0, stream>>>(ue, ie, egoA, out);

    const float* ein = egoA;
    float*       eout = egoB;
    for (int k = 0; k < 3; ++k) {
        fused_layer<<<(N_TOT + 63) / 64, 256, 0, stream>>>(row_ptr, epack, ein,
                                                           Wg[k], bg[k], Wb[k], bb[k],
                                                           eout, out, k);
        const float* t = ein; ein = eout; eout = (float*)t;
    }
}

// Round 3
// 794.712 us; speedup vs baseline: 1.3865x; 1.3865x over previous
//
#include <hip/hip_runtime.h>

#define N_TOT      150000
#define N_USER     50000
#define N_EDGE     2400000
#define DIM        64
#define OUT_STRIDE 256
#define SLOPE      0.2f
#define NB_SCAN    ((N_TOT + 255) / 256)   // 587

// ---- ws layout ----
// ego    : [N,64] fp32 (in-place across layers)
// side   : [N,64] fp32   (aliased as rank[E] during CSR build)
// epack  : [E] int2 (col, val_bits)
// row_ptr: [N+1] int
// cnt    : [N] int (histogram counts)
// bsum   : [NB_SCAN] int

__global__ void init_ego(const float* __restrict__ ue, const float* __restrict__ ie,
                         float* __restrict__ ego, float* __restrict__ out) {
    int idx = blockIdx.x * blockDim.x + threadIdx.x;          // float4 index
    if (idx >= N_TOT * DIM / 4) return;
    int n  = idx >> 4;
    int c4 = idx & 15;
    float4 v = (n < N_USER) ? ((const float4*)ue)[idx]
                            : ((const float4*)ie)[idx - N_USER * (DIM / 4)];
    ((float4*)ego)[idx] = v;
    ((float4*)out)[n * (OUT_STRIDE / 4) + c4] = v;
}

// Histogram + per-edge rank in ONE pass: the atomic return value IS the rank.
// 4 edges per thread (int4 reads) for ILP on the atomic round-trips.
// (8-edge variant measured SLOWER in round 2 — halved grid cut resident waves.)
__global__ void hist_rank(const int* __restrict__ rows, int* __restrict__ cnt,
                          int* __restrict__ rank) {
    int t = blockIdx.x * blockDim.x + threadIdx.x;
    if (t >= N_EDGE / 4) return;
    int4 r4 = ((const int4*)rows)[t];
    int4 k4;
    k4.x = atomicAdd(&cnt[r4.x], 1);
    k4.y = atomicAdd(&cnt[r4.y], 1);
    k4.z = atomicAdd(&cnt[r4.z], 1);
    k4.w = atomicAdd(&cnt[r4.w], 1);
    ((int4*)rank)[t] = k4;
}

// Hierarchical scan, stage 1: per-256-chunk exclusive scan + block totals.
__global__ __launch_bounds__(256) void scan_partial(const int* __restrict__ cnt,
                                                    int* __restrict__ row_ptr,
                                                    int* __restrict__ bsum) {
    __shared__ int s[256];
    int tid = threadIdx.x;
    int i = blockIdx.x * 256 + tid;
    int v = (i < N_TOT) ? cnt[i] : 0;
    s[tid] = v;
    __syncthreads();
    for (int off = 1; off < 256; off <<= 1) {                 // Hillis-Steele inclusive
        int t = (tid >= off) ? s[tid - off] : 0;
        __syncthreads();
        s[tid] += t;
        __syncthreads();
    }
    if (i < N_TOT) row_ptr[i] = s[tid] - v;                   // local exclusive
    if (tid == 255) bsum[blockIdx.x] = s[255];
}

// Stage 2: single block scans the NB_SCAN block totals (exclusive, in place).
__global__ __launch_bounds__(1024) void scan_bsums(int* __restrict__ bsum) {
    __shared__ int s[1024];
    int tid = threadIdx.x;
    int v = (tid < NB_SCAN) ? bsum[tid] : 0;
    s[tid] = v;
    __syncthreads();
    for (int off = 1; off < 1024; off <<= 1) {
        int t = (tid >= off) ? s[tid - off] : 0;
        __syncthreads();
        s[tid] += t;
        __syncthreads();
    }
    if (tid < NB_SCAN) bsum[tid] = s[tid] - v;
}

// Stage 3: add block offsets; write final row_ptr.
__global__ __launch_bounds__(256) void add_offsets(int* __restrict__ row_ptr,
                                                   const int* __restrict__ bsum) {
    int i = blockIdx.x * 256 + threadIdx.x;
    if (i < N_TOT) row_ptr[i] += bsum[blockIdx.x];
    if (i == 0) row_ptr[N_TOT] = N_EDGE;
}

// Atomic-free scatter: pos = row_ptr[row] + rank (deterministic). Pure
// streaming reads + one random 8B write per edge. 4 edges/thread for MLP.
__global__ void scatter_edges(const int* __restrict__ rows, const int* __restrict__ cols,
                              const float* __restrict__ vals,
                              const int* __restrict__ row_ptr,
                              const int* __restrict__ rank, int2* __restrict__ epack) {
    int t = blockIdx.x * blockDim.x + threadIdx.x;
    if (t >= N_EDGE / 4) return;
    int4   r4 = ((const int4*)rows)[t];
    int4   k4 = ((const int4*)rank)[t];
    int4   c4 = ((const int4*)cols)[t];
    float4 v4 = ((const float4*)vals)[t];
    epack[row_ptr[r4.x] + k4.x] = make_int2(c4.x, __float_as_int(v4.x));
    epack[row_ptr[r4.y] + k4.y] = make_int2(c4.y, __float_as_int(v4.y));
    epack[row_ptr[r4.z] + k4.z] = make_int2(c4.z, __float_as_int(v4.z));
    epack[row_ptr[r4.w] + k4.w] = make_int2(c4.w, __float_as_int(v4.w));
}

// side = A @ ego (CSR gather). One wave per row; 4 edge-groups x 16 lanes,
// float4 per lane. 16-edge unrolled head: 2 independent epack loads -> 4
// gathers (4 KB/wave) in flight. Per-group edge order identical to the
// 8-edge loop, so summation is bitwise-identical.
__global__ __launch_bounds__(256) void spmm_gather(
    const int* __restrict__ row_ptr, const int2* __restrict__ epack,
    const float* __restrict__ ego, float* __restrict__ side) {
    int lane = threadIdx.x & 63;
    int row  = blockIdx.x * 4 + (threadIdx.x >> 6);
    if (row >= N_TOT) return;
    int beg = row_ptr[row];
    int end = row_ptr[row + 1];
    int g = lane >> 4;          // edge sub-group 0..3
    int q = lane & 15;          // dim quarter: dims q*4 .. q*4+3
    float4 acc = make_float4(0.f, 0.f, 0.f, 0.f);
    int i = beg;
    for (; i + 16 <= end; i += 16) {
        int4 e0 = ((const int4*)(epack + i))[g];              // edges i+2g, i+2g+1
        int4 e1 = ((const int4*)(epack + i + 8))[g];          // edges i+8+2g, i+8+2g+1
        float4 va = ((const float4*)(ego + (size_t)e0.x * DIM))[q];
        float4 vb = ((const float4*)(ego + (size_t)e0.z * DIM))[q];
        float4 vc = ((const float4*)(ego + (size_t)e1.x * DIM))[q];
        float4 vd = ((const float4*)(ego + (size_t)e1.z * DIM))[q];
        float wa = __int_as_float(e0.y);
        float wb = __int_as_float(e0.w);
        float wc = __int_as_float(e1.y);
        float wd = __int_as_float(e1.w);
        acc.x = fmaf(wa, va.x, acc.x); acc.y = fmaf(wa, va.y, acc.y);
        acc.z = fmaf(wa, va.z, acc.z); acc.w = fmaf(wa, va.w, acc.w);
        acc.x = fmaf(wb, vb.x, acc.x); acc.y = fmaf(wb, vb.y, acc.y);
        acc.z = fmaf(wb, vb.z, acc.z); acc.w = fmaf(wb, vb.w, acc.w);
        acc.x = fmaf(wc, vc.x, acc.x); acc.y = fmaf(wc, vc.y, acc.y);
        acc.z = fmaf(wc, vc.z, acc.z); acc.w = fmaf(wc, vc.w, acc.w);
        acc.x = fmaf(wd, vd.x, acc.x); acc.y = fmaf(wd, vd.y, acc.y);
        acc.z = fmaf(wd, vd.z, acc.z); acc.w = fmaf(wd, vd.w, acc.w);
    }
    for (; i + 8 <= end; i += 8) {
        int4 ee = ((const int4*)(epack + i))[g];
        float4 va = ((const float4*)(ego + (size_t)ee.x * DIM))[q];
        float4 vb = ((const float4*)(ego + (size_t)ee.z * DIM))[q];
        float wa = __int_as_float(ee.y);
        float wb = __int_as_float(ee.w);
        acc.x = fmaf(wa, va.x, acc.x); acc.y = fmaf(wa, va.y, acc.y);
        acc.z = fmaf(wa, va.z, acc.z); acc.w = fmaf(wa, va.w, acc.w);
        acc.x = fmaf(wb, vb.x, acc.x); acc.y = fmaf(wb, vb.y, acc.y);
        acc.z = fmaf(wb, vb.z, acc.z); acc.w = fmaf(wb, vb.w, acc.w);
    }
    for (; i < end; i += 4) {                                 // tail: <=7 edges
        if (i + g < end) {
            int2 e = epack[i + g];
            float4 v = ((const float4*)(ego + (size_t)e.x * DIM))[q];
            float w = __int_as_float(e.y);
            acc.x = fmaf(w, v.x, acc.x); acc.y = fmaf(w, v.y, acc.y);
            acc.z = fmaf(w, v.z, acc.z); acc.w = fmaf(w, v.w, acc.w);
        }
    }
    // combine the 4 edge-groups (lane bits 4 and 5)
    acc.x += __shfl_xor(acc.x, 16, 64); acc.y += __shfl_xor(acc.y, 16, 64);
    acc.z += __shfl_xor(acc.z, 16, 64); acc.w += __shfl_xor(acc.w, 16, 64);
    acc.x += __shfl_xor(acc.x, 32, 64); acc.y += __shfl_xor(acc.y, 32, 64);
    acc.z += __shfl_xor(acc.z, 32, 64); acc.w += __shfl_xor(acc.w, 32, 64);
    if (g == 0)
        *(float4*)(side + (size_t)row * DIM + q * 4) = acc;
}

// Dual 64x64 GEMM + LeakyReLU + add + l2norm per 64-row tile.
// p = ego*side computed during staging; ego updated IN PLACE (block owns its rows).
__global__ __launch_bounds__(256) void transform_gemm(
    const float* __restrict__ Wg, const float* __restrict__ bgv,
    const float* __restrict__ Wb, const float* __restrict__ bbv,
    const float* __restrict__ side, float* __restrict__ ego,
    float* __restrict__ out, int layer) {
    __shared__ float sST[DIM][68];     // sST[k][r] = side[R0+r][k]
    __shared__ float sPT[DIM][68];     // sPT[k][r] = (ego*side)[R0+r][k]
    __shared__ float sWg[DIM][DIM];
    __shared__ float sWb[DIM][DIM];
    int tid = threadIdx.x;
    int R0  = blockIdx.x * 64;

    #pragma unroll
    for (int it = 0; it < 4; ++it) {                          // stage W matrices
        int f = tid + it * 256;                               // float4 idx 0..1023
        float4 wg = ((const float4*)Wg)[f];
        float4 wb = ((const float4*)Wb)[f];
        int k = f >> 4, c = (f & 15) * 4;
        *(float4*)&sWg[k][c] = wg;
        *(float4*)&sWb[k][c] = wb;
    }
    #pragma unroll
    for (int it = 0; it < 4; ++it) {                          // stage side/p transposed
        int f  = tid + it * 256;
        int r  = f >> 4, k0 = (f & 15) * 4;
        int row = R0 + r;
        float4 s4 = make_float4(0.f, 0.f, 0.f, 0.f);
        float4 e4 = make_float4(0.f, 0.f, 0.f, 0.f);
        if (row < N_TOT) {
            s4 = *(const float4*)&side[(size_t)row * DIM + k0];
            e4 = *(const float4*)&ego [(size_t)row * DIM + k0];
        }
        sST[k0 + 0][r] = s4.x; sST[k0 + 1][r] = s4.y;
        sST[k0 + 2][r] = s4.z; sST[k0 + 3][r] = s4.w;
        sPT[k0 + 0][r] = s4.x * e4.x; sPT[k0 + 1][r] = s4.y * e4.y;
        sPT[k0 + 2][r] = s4.z * e4.z; sPT[k0 + 3][r] = s4.w * e4.w;
    }
    __syncthreads();

    int tx = tid & 15, ty = tid >> 4;
    int c0 = tx * 4, r0 = ty * 4;
    float ag[4][4] = {{0.f}}, ab[4][4] = {{0.f}};
    #pragma unroll 4
    for (int k = 0; k < DIM; ++k) {
        float4 s4 = *(const float4*)&sST[k][r0];
        float4 p4 = *(const float4*)&sPT[k][r0];
        float4 g4 = *(const float4*)&sWg[k][c0];
        float4 b4 = *(const float4*)&sWb[k][c0];
        float ss[4] = {s4.x, s4.y, s4.z, s4.w};
        float pp[4] = {p4.x, p4.y, p4.z, p4.w};
        float gg[4] = {g4.x, g4.y, g4.z, g4.w};
        float bw[4] = {b4.x, b4.y, b4.z, b4.w};
        #pragma unroll
        for (int i = 0; i < 4; ++i)
            #pragma unroll
            for (int j = 0; j < 4; ++j) {
                ag[i][j] = fmaf(ss[i], gg[j], ag[i][j]);
                ab[i][j] = fmaf(pp[i], bw[j], ab[i][j]);
            }
    }

    float4 bg4 = *(const float4*)&bgv[c0];
    float4 bb4 = *(const float4*)&bbv[c0];
    float bgl[4] = {bg4.x, bg4.y, bg4.z, bg4.w};
    float bbl[4] = {bb4.x, bb4.y, bb4.z, bb4.w};

    float ne[4][4];
    float ss2[4];
    #pragma unroll
    for (int i = 0; i < 4; ++i) {
        float s = 0.f;
        #pragma unroll
        for (int j = 0; j < 4; ++j) {
            float g = ag[i][j] + bgl[j];
            float b = ab[i][j] + bbl[j];
            g = g > 0.f ? g : SLOPE * g;
            b = b > 0.f ? b : SLOPE * b;
            float v = g + b;
            ne[i][j] = v;
            s = fmaf(v, v, s);
        }
        ss2[i] = s;
    }
    #pragma unroll
    for (int m = 1; m < 16; m <<= 1) {                        // reduce across tx group
        #pragma unroll
        for (int i = 0; i < 4; ++i) ss2[i] += __shfl_xor(ss2[i], m, 64);
    }

    float* outbase = out + (size_t)(layer + 1) * DIM;
    #pragma unroll
    for (int i = 0; i < 4; ++i) {
        int row = R0 + r0 + i;
        if (row >= N_TOT) break;
        float inv = 1.f / fmaxf(sqrtf(ss2[i]), 1e-12f);
        float4 e4 = make_float4(ne[i][0], ne[i][1], ne[i][2], ne[i][3]);
        float4 o4 = make_float4(ne[i][0] * inv, ne[i][1] * inv, ne[i][2] * inv, ne[i][3] * inv);
        *(float4*)&ego[(size_t)row * DIM + c0] = e4;
        *(float4*)&outbase[(size_t)row * OUT_STRIDE + c0] = o4;
    }
}

extern "C" void kernel_launch(void* const* d_in, const int* in_sizes, int n_in,
                              void* d_out, int out_size, void* d_ws, size_t ws_size,
                              hipStream_t stream) {
    const float* ue = (const float*)d_in[0];
    const float* ie = (const float*)d_in[1];
    const float* Wg[3] = {(const float*)d_in[2], (const float*)d_in[6], (const float*)d_in[10]};
    const float* bg[3] = {(const float*)d_in[3], (const float*)d_in[7], (const float*)d_in[11]};
    const float* Wb[3] = {(const float*)d_in[4], (const float*)d_in[8], (const float*)d_in[12]};
    const float* bb[3] = {(const float*)d_in[5], (const float*)d_in[9], (const float*)d_in[13]};
    const float* vals = (const float*)d_in[14];
    const int*  rows  = (const int*)d_in[15];
    const int*  cols  = (const int*)d_in[16];
    float* out = (float*)d_out;

    float* ego     = (float*)d_ws;
    float* side    = ego + (size_t)N_TOT * DIM;
    int2*  epack   = (int2*)(side + (size_t)N_TOT * DIM);
    int*   row_ptr = (int*)(epack + N_EDGE);
    int*   cnt     = row_ptr + (N_TOT + 16);
    int*   bsum    = cnt + N_TOT;
    int*   rank    = (int*)side;      // alias: side unused until layer loop

    // CSR build (adj constant across layers)
    hipMemsetAsync(cnt, 0, (size_t)N_TOT * sizeof(int), stream);
    hist_rank<<<(N_EDGE / 4 + 255) / 256, 256, 0, stream>>>(rows, cnt, rank);
    scan_partial<<<NB_SCAN, 256, 0, stream>>>(cnt, row_ptr, bsum);
    scan_bsums<<<1, 1024, 0, stream>>>(bsum);
    add_offsets<<<NB_SCAN, 256, 0, stream>>>(row_ptr, bsum);
    scatter_edges<<<(N_EDGE / 4 + 255) / 256, 256, 0, stream>>>(rows, cols, vals,
                                                                row_ptr, rank, epack);

    init_ego<<<(N_TOT * DIM / 4 + 255) / 256, 256, 0, stream>>>(ue, ie, ego, out);

    for (int k = 0; k < 3; ++k) {
        spmm_gather<<<(N_TOT + 3) / 4, 256, 0, stream>>>(row_ptr, epack, ego, side);
        transform_gemm<<<(N_TOT + 63) / 64, 256, 0, stream>>>(Wg[k], bg[k], Wb[k], bb[k],
                                                              side, ego, out, k);
    }
}